// Round 2
// baseline (168.058 us; speedup 1.0000x reference)
//
#include <hip/hip_runtime.h>
#include <hip/hip_bf16.h>

#define KTOT   25088          // 2 * 256 * 49
#define HALF_K 12544
#define HID    512
#define SPLITK 16
#define KCHUNK (KTOT/SPLITK)  // 1568
#define KSTEPS (KCHUNK/32)    // 49

typedef __attribute__((ext_vector_type(8))) short short8;
typedef __attribute__((ext_vector_type(4))) float f32x4;

// ---------- feats [C,H,W] -> ft [map][y*32+x][c] (channel-contiguous) ----------
__global__ __launch_bounds__(256) void k_tfeat(const float* __restrict__ f1,
                                               const float* __restrict__ f2,
                                               float* __restrict__ ft) {
  __shared__ float tile[64][65];
  const int ct = blockIdx.x, yxt = blockIdx.y, map = blockIdx.z;
  const float* src = map ? f2 : f1;
  const int t = threadIdx.x, t4 = t >> 6, tl = t & 63;
#pragma unroll
  for (int pass = 0; pass < 16; ++pass) {
    int cl = pass * 4 + t4;
    tile[cl][tl] = src[(ct * 64 + cl) * 1024 + yxt * 64 + tl];
  }
  __syncthreads();
#pragma unroll
  for (int pass = 0; pass < 16; ++pass) {
    int yl = pass * 4 + t4;
    ft[(size_t)map * 262144 + (size_t)(yxt * 64 + yl) * 256 + ct * 64 + tl] = tile[tl][yl];
  }
}

// ---------- W1 [25088][512] -> W1t bf16 [512][25088'] with k' = map*12544 + p*256 + c ----------
__global__ __launch_bounds__(256) void k_tw1(const float* __restrict__ W1,
                                             __hip_bfloat16* __restrict__ W1t) {
  __shared__ float tile[64][65];
  const int ct = blockIdx.x & 3, jt = blockIdx.x >> 2;
  const int p = blockIdx.y, map = blockIdx.z;
  const int t = threadIdx.x, t4 = t >> 6, tl = t & 63;
#pragma unroll
  for (int pass = 0; pass < 16; ++pass) {
    int cl = pass * 4 + t4;
    int c = ct * 64 + cl;
    size_t krow = (size_t)map * HALF_K + (size_t)c * 49 + p;
    tile[cl][tl] = W1[krow * HID + jt * 64 + tl];
  }
  __syncthreads();
#pragma unroll
  for (int pass = 0; pass < 16; ++pass) {
    int jl = pass * 4 + t4;
    int j = jt * 64 + jl;
    W1t[(size_t)j * KTOT + (size_t)map * HALF_K + p * 256 + ct * 64 + tl] =
        __float2bfloat16(tile[tl][jl]);
  }
}

// ---------- RoIAlign: stage region in LDS + separable interp ----------
// block = (map, channel-half) x box; 256 threads: c = t&127, px-half = t>>7
__global__ __launch_bounds__(256) void k_roi(const float* __restrict__ ft,
                                             const float* __restrict__ props,
                                             __hip_bfloat16* __restrict__ A) {
  __shared__ __align__(16) float reg[12 * 12 * 128];   // 72 KB -> 2 blocks/CU
  __shared__ int gx0[14], gx1[14], gy0[14], gy1[14];
  __shared__ float glx[14], gvx[14], gly[14], gvy[14];
  __shared__ int gsc[4];
  __shared__ float sb3[2][128];
  const int map = blockIdx.x >> 1, ch0 = (blockIdx.x & 1) * 128;
  const int n = blockIdx.y, t = threadIdx.x;
  {
    const float sc = 1.0f / 32.0f;
    float bx1 = props[n * 4 + 0] * sc, by1 = props[n * 4 + 1] * sc;
    float bx2 = props[n * 4 + 2] * sc, by2 = props[n * 4 + 3] * sc;
    float bw = fmaxf(bx2 - bx1, 1.f) * (1.f / 7.f);
    float bh = fmaxf(by2 - by1, 1.f) * (1.f / 7.f);
    if (t < 32) {
      int i = t & 15;
      if (i < 14) {
        bool isY = t >= 16;
        float start = isY ? by1 : bx1;
        float bs = isY ? bh : bw;
        float o = start + (float)(i >> 1) * bs + ((float)(i & 1) + 0.5f) * bs * 0.5f;
        float v = (o >= -1.f && o <= 32.f) ? 1.f : 0.f;
        float oc = fminf(fmaxf(o, 0.f), 31.f);
        int i0 = (int)oc;
        int i1 = min(i0 + 1, 31);
        float l = oc - (float)i0;
        if (isY) { gy0[i] = i0; gy1[i] = i1; gly[i] = l; gvy[i] = v; }
        else     { gx0[i] = i0; gx1[i] = i1; glx[i] = l; gvx[i] = v; }
      }
    }
  }
  __syncthreads();
  if (t == 0) {
    gsc[0] = gx0[0]; gsc[1] = gy0[0];
    gsc[2] = gx1[13] - gx0[0] + 1;   // extx <= 12 (span 6.5*bw <= 9.3, +2)
    gsc[3] = gy1[13] - gy0[0] + 1;   // exty <= 12
  }
  __syncthreads();
  const int xs = gsc[0], ys = gsc[1], extx = gsc[2], exty = gsc[3];
  if (t < 14)      { gx0[t] -= xs; gx1[t] -= xs; }
  else if (t < 28) { gy0[t - 14] -= ys; gy1[t - 14] -= ys; }
  __syncthreads();
  // stage region rows (each row: extx*128 floats, contiguous 512B chunks)
  const float* fb = ft + (size_t)map * 262144 + ch0;
  for (int ry = 0; ry < exty; ++ry) {
    const float* grow = fb + ((size_t)((ys + ry) * 32 + xs)) * 256;
    float* lrow = &reg[ry * extx * 128];
    for (int j = t; j < extx * 32; j += 256) {
      int rx = j >> 5, c4 = (j & 31) * 4;
      *(float4*)&lrow[rx * 128 + c4] = *(const float4*)&grow[rx * 256 + c4];
    }
  }
  __syncthreads();
  // separable interp: x-interp each distinct row once (rolling 2-row cache)
  const int c = t & 127, bo = t >> 7;
  const int px0 = bo * 7;          // px range [px0, px0+7)
  float rowA[7], rowB[7];
  int iA = -1, iB = -1;
  __hip_bfloat16* outp = A + (size_t)n * KTOT + (size_t)map * HALF_K + ch0 + c;
  float bacc[4] = {0.f, 0.f, 0.f, 0.f};
#define LOADROW(dst, rr) { _Pragma("unroll") for (int q = 0; q < 7; ++q) { \
      int px = px0 + q; \
      const float* rp = &reg[(rr) * extx * 128 + c]; \
      float f0 = rp[gx0[px] * 128]; \
      float f1 = rp[gx1[px] * 128]; \
      dst[q] = gvx[px] * (f0 + (f1 - f0) * glx[px]); } }
  for (int oy = 0; oy < 7; ++oy) {
#pragma unroll
    for (int s = 0; s < 2; ++s) {
      int py = oy * 2 + s;
      int r0 = gy0[py], r1 = gy1[py];   // wave-uniform
      if (iA != r0) {
        if (iB == r0) {
#pragma unroll
          for (int q = 0; q < 7; ++q) rowA[q] = rowB[q];
          iA = r0;
        } else { LOADROW(rowA, r0); iA = r0; }
      }
      if (iB != r1) {
        if (iA == r1) {
#pragma unroll
          for (int q = 0; q < 7; ++q) rowB[q] = rowA[q];
          iB = r1;
        } else { LOADROW(rowB, r1); iB = r1; }
      }
      float ly = gly[py], vy = gvy[py];
      float w0 = vy * (1.f - ly), w1 = vy * ly;
#pragma unroll
      for (int q = 0; q < 7; ++q) bacc[(q + bo) >> 1] += w0 * rowA[q] + w1 * rowB[q];
    }
    // bo=0 holds bins ox0..2 + partial ox3; bo=1 partial ox3 + bins ox4..6
    if (bo == 0) sb3[0][c] = bacc[3]; else sb3[1][c] = bacc[0];
    __syncthreads();
    if (bo == 0) {
#pragma unroll
      for (int ox = 0; ox < 3; ++ox)
        outp[(oy * 7 + ox) * 256] = __float2bfloat16(0.25f * bacc[ox]);
      outp[(oy * 7 + 3) * 256] = __float2bfloat16(0.25f * (bacc[3] + sb3[1][c]));
    } else {
#pragma unroll
      for (int ox = 4; ox < 7; ++ox)
        outp[(oy * 7 + ox) * 256] = __float2bfloat16(0.25f * bacc[ox - 3]);
    }
    __syncthreads();
    bacc[0] = bacc[1] = bacc[2] = bacc[3] = 0.f;
  }
#undef LOADROW
}

// ---------- GEMM1: m97 structure, 128x128 tile, BK=32, 4 waves ----------
__device__ __forceinline__ void gl_lds16(const __hip_bfloat16* g, __hip_bfloat16* l) {
  __builtin_amdgcn_global_load_lds((const __attribute__((address_space(1))) void*)g,
                                   (__attribute__((address_space(3))) void*)l, 16, 0, 0);
}

__global__ __launch_bounds__(256) void k_gemm1(const __hip_bfloat16* __restrict__ A,
                                               const __hip_bfloat16* __restrict__ Bt,
                                               float* __restrict__ parts, int M) {
  __shared__ __align__(16) __hip_bfloat16 As[128 * 32];
  __shared__ __align__(16) __hip_bfloat16 Bs[128 * 32];
  const int t = threadIdx.x;
  const int row0 = blockIdx.x * 128, col0 = blockIdx.y * 128;
  const size_t k0 = (size_t)blockIdx.z * KCHUNK;
  // staging: issue q covers LDS rows q*64 + t/4, slot t%4 (linear dest);
  // source pre-swizzled: slot s = g ^ ((row>>1)&3); (row+64) keeps same s
  const int lr = t >> 2, lg = t & 3;
  const int sg = lg ^ ((lr >> 1) & 3);
  const __hip_bfloat16* ag0 = A  + (size_t)(row0 + lr) * KTOT + k0 + sg * 8;
  const __hip_bfloat16* ag1 = A  + (size_t)(row0 + 64 + lr) * KTOT + k0 + sg * 8;
  const __hip_bfloat16* bg0 = Bt + (size_t)(col0 + lr) * KTOT + k0 + sg * 8;
  const __hip_bfloat16* bg1 = Bt + (size_t)(col0 + 64 + lr) * KTOT + k0 + sg * 8;
  __hip_bfloat16* la0 = &As[t * 8];
  __hip_bfloat16* la1 = &As[2048 + t * 8];
  __hip_bfloat16* lb0 = &Bs[t * 8];
  __hip_bfloat16* lb1 = &Bs[2048 + t * 8];

  const int lane = t & 63, w = t >> 6;
  const int wr = (w >> 1) * 64, wc = (w & 1) * 64;
  const int r = lane & 15, g = lane >> 4;
  const int s = g ^ ((r >> 1) & 3);          // frag rows: (X16 + r)>>1 & 3 == (r>>1)&3
  const int iab = (wr + r) * 32 + s * 8;
  const int ibb = (wc + r) * 32 + s * 8;

  f32x4 acc[4][4];
#pragma unroll
  for (int m = 0; m < 4; ++m)
#pragma unroll
    for (int n = 0; n < 4; ++n) acc[m][n] = (f32x4){0.f, 0.f, 0.f, 0.f};

  for (int kt = 0; kt < KSTEPS; ++kt) {
    gl_lds16(ag0, la0); gl_lds16(ag1, la1);
    gl_lds16(bg0, lb0); gl_lds16(bg1, lb1);
    ag0 += 32; ag1 += 32; bg0 += 32; bg1 += 32;
    __syncthreads();               // drains vmcnt -> tiles ready
    short8 af[4], bf[4];
#pragma unroll
    for (int m = 0; m < 4; ++m) af[m] = *(const short8*)&As[iab + m * 512];
#pragma unroll
    for (int n = 0; n < 4; ++n) bf[n] = *(const short8*)&Bs[ibb + n * 512];
#pragma unroll
    for (int m = 0; m < 4; ++m)
#pragma unroll
      for (int n = 0; n < 4; ++n)
        acc[m][n] = __builtin_amdgcn_mfma_f32_16x16x32_bf16(af[m], bf[n], acc[m][n], 0, 0, 0);
    __syncthreads();               // reads done before next staging
  }
  float* P = parts + (size_t)blockIdx.z * ((size_t)M * HID);
#pragma unroll
  for (int m = 0; m < 4; ++m)
#pragma unroll
    for (int n = 0; n < 4; ++n)
#pragma unroll
      for (int q = 0; q < 4; ++q) {
        int rr = row0 + wr + m * 16 + g * 4 + q;
        int cc = col0 + wc + n * 16 + r;
        P[(size_t)rr * HID + cc] = acc[m][n][q];
      }
}

// ---------- reduce split-K partials + bias + ReLU ----------
__global__ __launch_bounds__(256) void k_epi1(const float* __restrict__ parts,
                                              const float* __restrict__ b1,
                                              float* __restrict__ h, int M) {
  int idx = blockIdx.x * 256 + threadIdx.x;
  size_t stride = (size_t)M * HID;
  float s = b1[idx & (HID - 1)];
#pragma unroll
  for (int p = 0; p < SPLITK; ++p) s += parts[idx + (size_t)p * stride];
  h[idx] = fmaxf(s, 0.f);
}

// ---------- head: out = h @ W2 + b2, sigmoids, scatter ----------
__global__ __launch_bounds__(256) void k_head(const float* __restrict__ h,
                                              const float* __restrict__ W2,
                                              const float* __restrict__ b2,
                                              float* __restrict__ out, int N) {
  __shared__ float hrow[512];
  __shared__ float part[16][17];
  const int n = blockIdx.x, t = threadIdx.x;
  hrow[t]       = h[(size_t)n * HID + t];
  hrow[t + 256] = h[(size_t)n * HID + 256 + t];
  __syncthreads();
  int j = t & 15, kc = t >> 4;
  float a = 0.f;
  if (j < 11) {
#pragma unroll
    for (int kk = 0; kk < 32; ++kk) {
      int k = kc * 32 + kk;
      a += hrow[k] * W2[k * 11 + j];
    }
  }
  part[kc][j] = a;
  __syncthreads();
  if (t < 11) {
    float sm = b2[t];
#pragma unroll
    for (int k2 = 0; k2 < 16; ++k2) sm += part[k2][t];
    if (t == 0)      out[n] = 1.f / (1.f + expf(-sm));
    else if (t == 1) out[N + n] = 1.f / (1.f + expf(-sm));
    else if (t < 6)  out[2 * N + n * 4 + (t - 2)] = sm;
    else if (t < 10) out[6 * N + n * 4 + (t - 6)] = sm;
    else             out[10 * N + n] = 1.f / (1.f + expf(-sm));
  }
}

extern "C" void kernel_launch(void* const* d_in, const int* in_sizes, int n_in,
                              void* d_out, int out_size, void* d_ws, size_t ws_size,
                              hipStream_t stream) {
  const float* feats1 = (const float*)d_in[0];
  const float* feats2 = (const float*)d_in[1];
  const float* props  = (const float*)d_in[2];
  const float* W1     = (const float*)d_in[3];
  const float* b1     = (const float*)d_in[4];
  const float* W2     = (const float*)d_in[5];
  const float* b2     = (const float*)d_in[6];
  float* out = (float*)d_out;
  const int N = in_sizes[2] / 4;   // 1024

  char* ws = (char*)d_ws;
  float* ft = (float*)ws;                                          // 2 MB
  __hip_bfloat16* Abuf = (__hip_bfloat16*)(ws + (2u << 20));       // 49 MB
  size_t offW1t = (2u << 20) + (size_t)N * KTOT * 2;
  __hip_bfloat16* W1t = (__hip_bfloat16*)(ws + offW1t);            // 24.5 MB
  size_t offParts = offW1t + (size_t)HID * KTOT * 2;
  float* parts = (float*)(ws + offParts);                          // 32 MB
  size_t offH = offParts + (size_t)SPLITK * N * HID * 4;
  float* h = (float*)(ws + offH);                                  // 2 MB

  k_tfeat<<<dim3(4, 16, 2), 256, 0, stream>>>(feats1, feats2, ft);
  k_tw1<<<dim3(32, 49, 2), 256, 0, stream>>>(W1, W1t);
  k_roi<<<dim3(4, N), 256, 0, stream>>>(ft, props, Abuf);
  k_gemm1<<<dim3(N / 128, HID / 128, SPLITK), 256, 0, stream>>>(Abuf, W1t, parts, N);
  k_epi1<<<dim3((N * HID) / 256), 256, 0, stream>>>(parts, b1, h, N);
  k_head<<<dim3(N), 256, 0, stream>>>(h, W2, b2, out, N);
}